// Round 1
// 240.009 us; speedup vs baseline: 1.2189x; 1.2189x over previous
//
#include <hip/hip_runtime.h>
#include <math.h>

// CausalSemanticGrouping: key [B,N,D] fp32, slot_embed [K,D] fp32
#define BB 64
#define NN 1024
#define DD 512
#define KK 64
#define CC 1088           // K + N
#define NCT 17            // C / 64
#define INVT 14.285714285714286f   // 1 / 0.07

// d_out: out [B,K,D] fp32 then dots [B,K,C] fp32.
// d_ws (floats): denomP [B*K][34] partial exp-sums (17 col-tiles x 2 col-halves).
//   Fully written by k_dots before k_out reads it -> no zero-init required.

typedef __bf16 bf16_t;
typedef __bf16 bf16x4 __attribute__((ext_vector_type(4)));
typedef __bf16 bf16x8 __attribute__((ext_vector_type(8)));
typedef float f32x16 __attribute__((ext_vector_type(16)));

// split x into bf16 hi + bf16 lo, x ~= hi + lo with ~2^-16 relative error
__device__ __forceinline__ void split4(float4 x, bf16x4& hi, bf16x4& lo) {
    float v[4] = {x.x, x.y, x.z, x.w};
    #pragma unroll
    for (int j = 0; j < 4; j++) {
        __bf16 h = (__bf16)v[j];
        hi[j] = h;
        lo[j] = (__bf16)(v[j] - (float)h);
    }
}

// dots[b, 0:64, ct*64:+64] via split-bf16 32x32x16 MFMA (3 mfma/k-step).
// Fused: slot/key L2-norms from staging regs; masked exp row-partials -> denomP.
// T14 prefetch: issue next tile's global loads before MFMA phase. grid (17, B) x 256.
__global__ __launch_bounds__(256, 3) void k_dots(const float* __restrict__ key,
                                                 const float* __restrict__ slot,
                                                 float* __restrict__ dots,
                                                 float* __restrict__ denomP) {
    __shared__ __align__(16) bf16_t Ahi[64][72], Alo[64][72];
    __shared__ __align__(16) bf16_t Bhi[64][72], Blo[64][72];
    __shared__ float srA[64], srB[64];
    const int b = blockIdx.y, ct = blockIdx.x;
    const int tid = threadIdx.x;
    const int w = tid >> 6, lane = tid & 63;
    const int mw = (w >> 1) * 32, nw = (w & 1) * 32;
    const int g = tid & 15, r0 = tid >> 4;       // staging: rows r0+i*16, cols g*4..+4

    const float* ap[4];
    const float* bp[4];
    #pragma unroll
    for (int i = 0; i < 4; i++) {
        int r = r0 + i * 16;
        ap[i] = slot + (size_t)r * DD + g * 4;
        int c = ct * 64 + r;
        bp[i] = (c < KK) ? (slot + (size_t)c * DD + g * 4)
                         : (key + ((size_t)b * NN + (c - KK)) * DD + g * 4);
    }

    float4 ra[4], rb[4];
    float sqA[4] = {0.f, 0.f, 0.f, 0.f}, sqB[4] = {0.f, 0.f, 0.f, 0.f};
    f32x16 acc = {};

    auto load_tile = [&](int k0) {
        #pragma unroll
        for (int i = 0; i < 4; i++) {
            ra[i] = *(const float4*)(ap[i] + k0);
            rb[i] = *(const float4*)(bp[i] + k0);
        }
    };
    auto stage_tile = [&]() {
        #pragma unroll
        for (int i = 0; i < 4; i++) {
            int r = r0 + i * 16;
            sqA[i] += ra[i].x * ra[i].x + ra[i].y * ra[i].y
                    + ra[i].z * ra[i].z + ra[i].w * ra[i].w;
            sqB[i] += rb[i].x * rb[i].x + rb[i].y * rb[i].y
                    + rb[i].z * rb[i].z + rb[i].w * rb[i].w;
            bf16x4 h, l;
            split4(ra[i], h, l);
            *(bf16x4*)&Ahi[r][g * 4] = h;
            *(bf16x4*)&Alo[r][g * 4] = l;
            split4(rb[i], h, l);
            *(bf16x4*)&Bhi[r][g * 4] = h;
            *(bf16x4*)&Blo[r][g * 4] = l;
        }
    };

    load_tile(0);
    stage_tile();
    __syncthreads();

    for (int k0 = 0; k0 < DD; k0 += 64) {
        if (k0 + 64 < DD) load_tile(k0 + 64);     // in flight across MFMA phase
        #pragma unroll
        for (int kk = 0; kk < 64; kk += 16) {
            bf16x8 ah = *(bf16x8*)&Ahi[mw + (lane & 31)][kk + (lane >> 5) * 8];
            bf16x8 al = *(bf16x8*)&Alo[mw + (lane & 31)][kk + (lane >> 5) * 8];
            bf16x8 bh = *(bf16x8*)&Bhi[nw + (lane & 31)][kk + (lane >> 5) * 8];
            bf16x8 bl = *(bf16x8*)&Blo[nw + (lane & 31)][kk + (lane >> 5) * 8];
            acc = __builtin_amdgcn_mfma_f32_32x32x16_bf16(ah, bh, acc, 0, 0, 0);
            acc = __builtin_amdgcn_mfma_f32_32x32x16_bf16(ah, bl, acc, 0, 0, 0);
            acc = __builtin_amdgcn_mfma_f32_32x32x16_bf16(al, bh, acc, 0, 0, 0);
        }
        __syncthreads();
        if (k0 + 64 < DD) {
            stage_tile();
            __syncthreads();
        }
    }

    // ---- norms: partial sumsq -> LDS (reuse fragment LDS, all MFMA reads done) ----
    float* SA = (float*)&Ahi[0][0];   // [64][17]
    float* SB = (float*)&Bhi[0][0];
    #pragma unroll
    for (int i = 0; i < 4; i++) {
        int r = r0 + i * 16;
        SA[r * 17 + g] = sqA[i];
        SB[r * 17 + g] = sqB[i];
    }
    __syncthreads();
    if (tid < 128) {
        int rr = tid & 63;
        const float* S = (tid < 64) ? SA : SB;
        float s = 0.f;
        #pragma unroll
        for (int j = 0; j < 16; j++) s += S[rr * 17 + j];
        float rv = 1.0f / fmaxf(sqrtf(s), 1e-12f);
        if (tid < 64) srA[rr] = rv; else srB[rr] = rv;
    }
    __syncthreads();

    // ---- epilogue: scale, write dots, masked-exp row partials ----
    const int n = nw + (lane & 31);
    const int c = ct * 64 + n;
    const float rn = srB[n];
    #pragma unroll
    for (int reg = 0; reg < 16; reg++) {
        int m = mw + (reg & 3) + 8 * (reg >> 2) + 4 * (lane >> 5);
        float v = acc[reg] * srA[m] * rn;
        dots[((size_t)b * KK + m) * CC + c] = v;
        // mask: slot m attends slots < m (strict) and all keys
        float e = ((c >= KK) || (c < m)) ? __expf(v * INVT) : 0.0f;
        #pragma unroll
        for (int off = 16; off > 0; off >>= 1) e += __shfl_xor(e, off, 64);
        if ((lane & 31) == 0)
            denomP[((size_t)b * KK + m) * 34 + ct * 2 + (w & 1)] = e;
    }
}

// out[b, 0:64, d0:+64] = softmax-normalized(dots) x V, flash-style: exp+invden
// applied during A staging; V transposed in LDS; T14 prefetch. grid (8, B) x 256,
// XCD-bijective swizzle so all 8 d-blocks of one b share an XCD L2 (dots[b] hits L2).
__global__ __launch_bounds__(256, 3) void k_out(const float* __restrict__ key,
                                                const float* __restrict__ slot,
                                                const float* __restrict__ dots,
                                                const float* __restrict__ denomP,
                                                float* __restrict__ out) {
    __shared__ __align__(16) bf16_t Ahi[64][72], Alo[64][72];
    __shared__ __align__(16) bf16_t Vhi[64][72], Vlo[64][72];   // [d][c] transposed
    __shared__ float sd[64];
    // dispatch-linear index: x fastest. b = (q<<3)|(s&7) -> blocks of same b land
    // on the same XCD under round-robin (i mod 8) placement; bijective remap.
    const int flat = blockIdx.x + blockIdx.y * 8;
    const int q = flat >> 6, s = flat & 63;
    const int b = (q << 3) | (s & 7);
    const int d0 = (s >> 3) * 64;
    const int tid = threadIdx.x;
    const int w = tid >> 6, lane = tid & 63;
    const int mw = (w >> 1) * 32, nw = (w & 1) * 32;
    const int g = tid & 15, r0 = tid >> 4;
    const int cpair = tid & 31, dg = tid >> 5;    // V staging roles

    if (tid < 64) {
        const float* dp = denomP + ((size_t)b * KK + tid) * 34;
        float ssum = 0.f;
        #pragma unroll
        for (int j = 0; j < 34; j++) ssum += dp[j];
        sd[tid] = 1.0f / (ssum * (1.0f + 1e-7f));
    }
    __syncthreads();
    float sdr[4];
    #pragma unroll
    for (int i = 0; i < 4; i++) sdr[i] = sd[r0 + i * 16];

    const float* adp[4];
    #pragma unroll
    for (int i = 0; i < 4; i++)
        adp[i] = dots + ((size_t)b * KK + (r0 + i * 16)) * CC + g * 4;

    float4 ra[4], v0a, v0b, v1a, v1b;
    f32x16 acc = {};

    auto load_tile = [&](int c0) {
        #pragma unroll
        for (int i = 0; i < 4; i++) ra[i] = *(const float4*)(adp[i] + c0);
        int c = c0 + 2 * cpair;
        const float* p0 = (c < KK) ? (slot + (size_t)c * DD)
                                   : (key + ((size_t)b * NN + (c - KK)) * DD);
        const float* p1 = (c + 1 < KK) ? (slot + (size_t)(c + 1) * DD)
                                       : (key + ((size_t)b * NN + (c + 1 - KK)) * DD);
        p0 += d0 + dg * 8;
        p1 += d0 + dg * 8;
        v0a = *(const float4*)p0;
        v0b = *(const float4*)(p0 + 4);
        v1a = *(const float4*)p1;
        v1b = *(const float4*)(p1 + 4);
    };
    auto stage_tile = [&](int c0) {
        #pragma unroll
        for (int i = 0; i < 4; i++) {
            int r = r0 + i * 16;
            float av[4] = {ra[i].x, ra[i].y, ra[i].z, ra[i].w};
            float pv[4];
            #pragma unroll
            for (int j = 0; j < 4; j++) {
                int c = c0 + g * 4 + j;
                pv[j] = ((c >= KK) || (c < r)) ? __expf(av[j] * INVT) * sdr[i] : 0.0f;
            }
            bf16x4 h, l;
            #pragma unroll
            for (int j = 0; j < 4; j++) {
                __bf16 hh = (__bf16)pv[j];
                h[j] = hh;
                l[j] = (__bf16)(pv[j] - (float)hh);
            }
            *(bf16x4*)&Ahi[r][g * 4] = h;
            *(bf16x4*)&Alo[r][g * 4] = l;
        }
        bf16x4 h0a, l0a, h0b, l0b, h1a, l1a, h1b, l1b;
        split4(v0a, h0a, l0a); split4(v0b, h0b, l0b);
        split4(v1a, h1a, l1a); split4(v1b, h1b, l1b);
        #pragma unroll
        for (int j = 0; j < 8; j++) {
            __bf16 h0 = (j < 4) ? h0a[j] : h0b[j - 4];
            __bf16 l0 = (j < 4) ? l0a[j] : l0b[j - 4];
            __bf16 h1 = (j < 4) ? h1a[j] : h1b[j - 4];
            __bf16 l1 = (j < 4) ? l1a[j] : l1b[j - 4];
            unsigned hw = (unsigned)__builtin_bit_cast(unsigned short, h0)
                        | ((unsigned)__builtin_bit_cast(unsigned short, h1) << 16);
            unsigned lw = (unsigned)__builtin_bit_cast(unsigned short, l0)
                        | ((unsigned)__builtin_bit_cast(unsigned short, l1) << 16);
            *(unsigned*)&Vhi[dg * 8 + j][2 * cpair] = hw;
            *(unsigned*)&Vlo[dg * 8 + j][2 * cpair] = lw;
        }
    };

    load_tile(0);
    stage_tile(0);
    __syncthreads();

    for (int t = 0; t < NCT; t++) {
        int c0 = t * 64;
        if (t + 1 < NCT) load_tile(c0 + 64);      // in flight across MFMA phase
        #pragma unroll
        for (int kk = 0; kk < 64; kk += 16) {
            bf16x8 ah = *(bf16x8*)&Ahi[mw + (lane & 31)][kk + (lane >> 5) * 8];
            bf16x8 al = *(bf16x8*)&Alo[mw + (lane & 31)][kk + (lane >> 5) * 8];
            bf16x8 vh = *(bf16x8*)&Vhi[nw + (lane & 31)][kk + (lane >> 5) * 8];
            bf16x8 vl = *(bf16x8*)&Vlo[nw + (lane & 31)][kk + (lane >> 5) * 8];
            acc = __builtin_amdgcn_mfma_f32_32x32x16_bf16(ah, vh, acc, 0, 0, 0);
            acc = __builtin_amdgcn_mfma_f32_32x32x16_bf16(ah, vl, acc, 0, 0, 0);
            acc = __builtin_amdgcn_mfma_f32_32x32x16_bf16(al, vh, acc, 0, 0, 0);
        }
        __syncthreads();
        if (t + 1 < NCT) {
            stage_tile(c0 + 64);
            __syncthreads();
        }
    }

    const int d = d0 + nw + (lane & 31);
    #pragma unroll
    for (int reg = 0; reg < 16; reg++) {
        int m = mw + (reg & 3) + 8 * (reg >> 2) + 4 * (lane >> 5);
        out[((size_t)b * KK + m) * DD + d] = acc[reg];
    }
}

extern "C" void kernel_launch(void* const* d_in, const int* in_sizes, int n_in,
                              void* d_out, int out_size, void* d_ws, size_t ws_size,
                              hipStream_t stream) {
    const float* key  = (const float*)d_in[0];   // [B, N, D]
    const float* slot = (const float*)d_in[1];   // [K, D]
    float* out  = (float*)d_out;                        // [B, K, D]
    float* dots = out + (size_t)BB * KK * DD;           // [B, K, C]
    float* denomP = (float*)d_ws;                       // [B*K][34]

    k_dots<<<dim3(NCT, BB), dim3(256), 0, stream>>>(key, slot, dots, denomP);
    k_out<<<dim3(DD / 64, BB), dim3(256), 0, stream>>>(key, slot, dots, denomP, out);
}